// Round 4
// baseline (424.300 us; speedup 1.0000x reference)
//
#include <hip/hip_runtime.h>
#include <hip/hip_cooperative_groups.h>

namespace cg = cooperative_groups;

// Problem constants (match reference)
#define N_NODES 4096
#define N_EDGES 131072
#define D_FEAT  512
#define K_SEL   2048      // ceil(0.5 * 4096)
#define MAXDEG  128       // slot capacity per node (mean deg 32, max ~55)
#define NWORDS  128       // 4096 bits / 32
#define NBLK    1024
#define NTHR    256

// Single cooperative kernel: zero -> build -> score -> rank+gather -> adj,
// with grid-wide barriers between phases (eliminates 4 inter-kernel gaps).
__global__ __launch_bounds__(NTHR, 4) void fused_kernel(
    const int* __restrict__ src, const int* __restrict__ dst,
    const float* __restrict__ att, const int* __restrict__ batch,
    const int* __restrict__ dir_p, const float* __restrict__ x,
    unsigned* __restrict__ B, unsigned* __restrict__ cnt,
    unsigned* __restrict__ slots, float* __restrict__ scores,
    unsigned* __restrict__ permw,
    float* __restrict__ out_x, float* __restrict__ out_adj,
    float* __restrict__ out_batch, float* __restrict__ out_perm)
{
    cg::grid_group grid = cg::this_grid();
    const int t = threadIdx.x;
    const int blk = blockIdx.x;
    const int gtid = blk * NTHR + t;
    const int wave = t >> 6, lane = t & 63;

    __shared__ float a_ord[4][MAXDEG];      // 2 KiB (score phase)
    __shared__ unsigned nbr[MAXDEG];        // adj phase
    __shared__ unsigned rowH[2][NWORDS];    // adj phase

    // ---- phase 0: zero B (524288 u32) + cnt (4096 u32), contiguous in ws ----
    if (gtid < (N_NODES * NWORDS + N_NODES) / 4)
        ((uint4*)B)[gtid] = make_uint4(0u, 0u, 0u, 0u);
    grid.sync();

    // ---- phase 1: build per-node slot lists (unordered) + out-neighbor bitsets ----
    // slots[s][pos] = (eidx << 12) | dst. atomicAdd order nondeterministic but all
    // consumers are order-independent (score re-sorts by eidx; B/adj are ORs).
    if (gtid < N_EDGES) {
        int s = src[gtid];
        int d = dst[gtid];
        unsigned pos = atomicAdd(&cnt[s], 1u);
        if (pos < MAXDEG) slots[((unsigned)s << 7) + pos] = ((unsigned)gtid << 12) | (unsigned)d;
        atomicOr(&B[((size_t)s << 7) + (unsigned)(d >> 5)], 1u << (d & 31));
    }
    grid.sync();

    // ---- phase 2: score; one WAVE per node, exact edge-order fp32 sum ----
    {
        int n = blk * 4 + wave;              // 1024 blocks x 4 waves = 4096 nodes
        unsigned nb = (unsigned)n << 7;
        unsigned d = min(cnt[n], (unsigned)MAXDEG);
        unsigned v0 = (lane < (int)d)        ? slots[nb + lane]      : 0xFFFFFFFFu;
        unsigned v1 = ((lane + 64) < (int)d) ? slots[nb + lane + 64] : 0xFFFFFFFFu;
        int r0 = 0, r1 = 0;
        int dk = (d < 64u) ? (int)d : 64;    // wave-uniform bound
        if (d <= 64u) {
            for (int k = 0; k < dk; ++k) {
                unsigned a = __shfl(v0, k);
                r0 += (a < v0);
            }
        } else {
            for (int k = 0; k < dk; ++k) {
                unsigned a = __shfl(v0, k);
                unsigned b = __shfl(v1, k);
                r0 += (a < v0) + (b < v0);
                r1 += (a < v1) + (b < v1);
            }
        }
        // scatter att into edge order (rank by packed key == rank by eidx)
        if (lane < (int)d)        a_ord[wave][r0] = att[v0 >> 12];
        if ((lane + 64) < (int)d) a_ord[wave][r1] = att[v1 >> 12];
        __syncthreads();
        if (lane == 0) {
            float sum = 0.0f;
            for (unsigned i = 0; i < d; ++i) sum += a_ord[wave][i];   // sequential, edge order
            float score = 0.0f;
            if (d > 0) {
                float df = (float)d;
                float mean = sum / df;                  // fl(att_sum / degree)
                score = ((float)dir_p[0] * mean) * df;  // (direction * att_mean) * degree
            }
            scores[n] = score;
        }
    }
    grid.sync();

    // ---- phase 3: exact stable descending rank + fused x gather ----
    {
        int n = blk * 4 + wave;
        float s = scores[n];
        const float4* sc4 = (const float4*)scores;
        int r = 0;
        #pragma unroll
        for (int i = 0; i < 16; ++i) {
            int q = lane + (i << 6);         // float4 index, coalesced, L1-resident
            float4 v = sc4[q];
            int m = q << 2;
            r += (v.x > s) || (v.x == s && (m + 0) < n);
            r += (v.y > s) || (v.y == s && (m + 1) < n);
            r += (v.z > s) || (v.z == s && (m + 2) < n);
            r += (v.w > s) || (v.w == s && (m + 3) < n);
        }
        #pragma unroll
        for (int off = 32; off; off >>= 1) r += __shfl_down(r, off);
        r = __shfl(r, 0);                    // broadcast rank
        if (r < K_SEL) {
            if (lane == 0) {
                permw[r] = (unsigned)n;
                out_perm[r] = (float)n;
                out_batch[r] = (float)batch[n];
            }
            // whole wave copies the selected x row: 512 floats = 128 float4
            const float4* xs = (const float4*)(x + (size_t)n * D_FEAT);
            float4* od = (float4*)(out_x + (size_t)r * D_FEAT);
            od[lane] = xs[lane];
            od[lane + 64] = xs[lane + 64];
        }
    }
    grid.sync();

    // ---- phase 4: 2-hop boolean adjacency; 2 selected rows per block ----
    for (int rr = 0; rr < 2; ++rr) {
        int p = blk * 2 + rr;
        __syncthreads();                     // protect LDS reuse across rows
        unsigned n = permw[p];
        unsigned d = min(cnt[n], (unsigned)MAXDEG);
        if (t < (int)d) nbr[t] = slots[((size_t)n << 7) + t] & 0xFFFu;
        __syncthreads();
        int w = t & 127, h = t >> 7;
        unsigned acc = 0;
        for (unsigned i = (unsigned)h; i < d; i += 2)
            acc |= B[((size_t)nbr[i] << 7) + w];   // 512B coalesced rows, L2-resident
        rowH[h][w] = acc;
        __syncthreads();
        if (t < NWORDS) rowH[0][t] |= rowH[1][t];
        __syncthreads();
        float4* o4 = (float4*)(out_adj + (size_t)p * K_SEL);
        #pragma unroll
        for (int i = 0; i < 2; ++i) {
            int q4 = t + (i << 8);           // 512 float4 per row
            int q = q4 << 2;
            unsigned c0 = permw[q], c1 = permw[q + 1], c2 = permw[q + 2], c3 = permw[q + 3];
            float4 v;
            v.x = (float)((rowH[0][c0 >> 5] >> (c0 & 31)) & 1u);
            v.y = (float)((rowH[0][c1 >> 5] >> (c1 & 31)) & 1u);
            v.z = (float)((rowH[0][c2 >> 5] >> (c2 & 31)) & 1u);
            v.w = (float)((rowH[0][c3 >> 5] >> (c3 & 31)) & 1u);
            o4[q4] = v;
        }
    }
}

extern "C" void kernel_launch(void* const* d_in, const int* in_sizes, int n_in,
                              void* d_out, int out_size, void* d_ws, size_t ws_size,
                              hipStream_t stream) {
    const float* x     = (const float*)d_in[0];
    const int*   eidx  = (const int*)d_in[1];
    const float* att   = (const float*)d_in[2];
    const int*   batch = (const int*)d_in[3];
    const int*   dir_p = (const int*)d_in[4];
    const int* src = eidx;
    const int* dst = eidx + N_EDGES;

    // workspace layout (bytes); B then cnt contiguous so one zero pass covers both
    char* ws = (char*)d_ws;
    unsigned* B      = (unsigned*)(ws + 0);        // 4096*128*4 = 2,097,152
    unsigned* cnt    = (unsigned*)(ws + 2097152);  // 16,384
    float*    scores = (float*)   (ws + 2113536);  // 16,384
    unsigned* permw  = (unsigned*)(ws + 2129920);  // 8,192
    unsigned* slots  = (unsigned*)(ws + 2138112);  // 2,097,152 (end ~4.24 MB)

    // output layout (floats)
    float* out_x     = (float*)d_out;                          // 2048*512
    float* out_adj   = out_x + (size_t)K_SEL * D_FEAT;         // 2048*2048
    float* out_batch = out_adj + (size_t)K_SEL * K_SEL;        // 2048
    float* out_perm  = out_batch + K_SEL;                      // 2048

    void* args[] = {
        (void*)&src, (void*)&dst, (void*)&att, (void*)&batch, (void*)&dir_p,
        (void*)&x, (void*)&B, (void*)&cnt, (void*)&slots, (void*)&scores,
        (void*)&permw, (void*)&out_x, (void*)&out_adj, (void*)&out_batch,
        (void*)&out_perm
    };
    hipLaunchCooperativeKernel((const void*)fused_kernel, dim3(NBLK), dim3(NTHR),
                               args, 0, stream);
}

// Round 5
// 43.571 us; speedup vs baseline: 9.7382x; 9.7382x over previous
//
#include <hip/hip_runtime.h>

// Problem constants (match reference)
#define N_NODES 4096
#define N_EDGES 131072
#define D_FEAT  512
#define K_SEL   2048      // ceil(0.5 * 4096)
#define MAXDEG  128       // slot capacity per node (mean deg 32, max ~55)
#define NWORDS  128       // 4096 bits / 32

// ---------------- stage 0: zero cnt only (16 KB) ----------------
__global__ void zero_cnt(unsigned* __restrict__ cnt) {
    cnt[blockIdx.x * 256 + threadIdx.x] = 0u;
}

// ---------------- stage 1: build per-node slot lists (unordered) ----------------
// slots[s][pos] = (eidx << 12) | dst  — eidx fits 17 bits, dst fits 12 bits.
// atomicAdd order is nondeterministic but all consumers are order-independent
// (score re-sorts by eidx; bitsets are ORs) -> outputs deterministic.
__global__ void build_kernel(const int* __restrict__ src, const int* __restrict__ dst,
                             unsigned* __restrict__ cnt, unsigned* __restrict__ slots) {
    int e = blockIdx.x * 512 + threadIdx.x;
    int s = src[e];
    int d = dst[e];
    unsigned pos = atomicAdd(&cnt[s], 1u);
    if (pos < MAXDEG) slots[((unsigned)s << 7) + pos] = ((unsigned)e << 12) | (unsigned)d;
}

// ---------------- stage 2: score (exact edge-order fp32 sum) + B bitset row ----------------
// One WAVE per node. The wave holds all the node's packed (eidx,dst) entries, so it
// both re-sorts attention into edge order AND constructs the full 512B out-neighbor
// bitset row in LDS -> coalesced write (B needs no pre-zero, no global atomics).
__global__ void score_kernel(const unsigned* __restrict__ cnt,
                             const unsigned* __restrict__ slots,
                             const float* __restrict__ att,
                             const int* __restrict__ dir_p,
                             float* __restrict__ scores,
                             unsigned* __restrict__ B) {
    __shared__ float a_ord[4][MAXDEG];     // 2 KiB
    __shared__ unsigned brow[4][NWORDS];   // 2 KiB
    int t = threadIdx.x, wave = t >> 6, lane = t & 63;
    int n = blockIdx.x * 4 + wave;         // 1024 blocks x 4 waves = 4096 nodes
    unsigned nb = (unsigned)n << 7;
    unsigned d = min(cnt[n], (unsigned)MAXDEG);
    // load up to 2 packed keys per lane; invalid -> UINT_MAX (sorts last, never used)
    unsigned v0 = (lane < (int)d)        ? slots[nb + lane]      : 0xFFFFFFFFu;
    unsigned v1 = ((lane + 64) < (int)d) ? slots[nb + lane + 64] : 0xFFFFFFFFu;

    // ---- bitset row (wave-private LDS, no block sync needed) ----
    brow[wave][lane] = 0u;
    brow[wave][lane + 64] = 0u;
    if (lane < (int)d)        atomicOr(&brow[wave][(v0 & 0xFFFu) >> 5], 1u << (v0 & 31));
    if ((lane + 64) < (int)d) atomicOr(&brow[wave][(v1 & 0xFFFu) >> 5], 1u << (v1 & 31));

    // ---- exact in-wave rank by packed key (== rank by edge index) ----
    int r0 = 0, r1 = 0;
    int dk = (d < 64u) ? (int)d : 64;      // wave-uniform bound
    if (d <= 64u) {
        for (int k = 0; k < dk; ++k) {
            unsigned a = __shfl(v0, k);
            r0 += (a < v0);
        }
    } else {
        for (int k = 0; k < dk; ++k) {
            unsigned a = __shfl(v0, k);
            unsigned b = __shfl(v1, k);
            r0 += (a < v0) + (b < v0);
            r1 += (a < v1) + (b < v1);
        }
    }
    if (lane < (int)d)        a_ord[wave][r0] = att[v0 >> 12];
    if ((lane + 64) < (int)d) a_ord[wave][r1] = att[v1 >> 12];
    __syncthreads();

    // coalesced B-row write (512B per wave)
    B[nb + lane] = brow[wave][lane];
    B[nb + lane + 64] = brow[wave][lane + 64];

    if (lane == 0) {
        float sum = 0.0f;
        for (unsigned i = 0; i < d; ++i) sum += a_ord[wave][i];   // sequential, edge order
        float score = 0.0f;
        if (d > 0) {
            float df = (float)d;
            float mean = sum / df;                  // fl(att_sum / degree)
            score = ((float)dir_p[0] * mean) * df;  // (direction * att_mean) * degree
        }
        scores[n] = score;
    }
}

// ---------------- stage 3: exact stable descending rank + fused x gather ----------------
__global__ void rank_kernel(const float* __restrict__ scores,
                            const int* __restrict__ batch,
                            const float* __restrict__ x,
                            unsigned* __restrict__ permw,
                            float* __restrict__ out_x,
                            float* __restrict__ out_batch,
                            float* __restrict__ out_perm) {
    int t = threadIdx.x, wave = t >> 6, lane = t & 63;
    int n = blockIdx.x * 4 + wave;       // 1024 blocks x 4 waves
    float s = scores[n];
    const float4* sc4 = (const float4*)scores;
    int r = 0;
    #pragma unroll
    for (int i = 0; i < 16; ++i) {
        int q = lane + (i << 6);         // float4 index, coalesced, cache-resident
        float4 v = sc4[q];
        int m = q << 2;
        r += (v.x > s) || (v.x == s && (m + 0) < n);
        r += (v.y > s) || (v.y == s && (m + 1) < n);
        r += (v.z > s) || (v.z == s && (m + 2) < n);
        r += (v.w > s) || (v.w == s && (m + 3) < n);
    }
    #pragma unroll
    for (int off = 32; off; off >>= 1) r += __shfl_down(r, off);
    r = __shfl(r, 0);                    // broadcast rank to all lanes
    if (r < K_SEL) {
        if (lane == 0) {
            permw[r] = (unsigned)n;
            out_perm[r] = (float)n;
            out_batch[r] = (float)batch[n];
        }
        // whole wave copies the selected x row: 512 floats = 128 float4
        const float4* xs = (const float4*)(x + (size_t)n * D_FEAT);
        float4* od = (float4*)(out_x + (size_t)r * D_FEAT);
        od[lane] = xs[lane];
        od[lane + 64] = xs[lane + 64];
    }
}

// ---------------- stage 4: 2-hop boolean adjacency among selected nodes ----------------
__global__ void adj_kernel(const unsigned* __restrict__ permw,
                           const unsigned* __restrict__ cnt,
                           const unsigned* __restrict__ slots,
                           const unsigned* __restrict__ B,
                           float* __restrict__ out_adj) {
    __shared__ unsigned nbr[MAXDEG];
    __shared__ unsigned rowH[2][NWORDS];
    int p = blockIdx.x, t = threadIdx.x;   // 256 threads
    unsigned n = permw[p];
    unsigned d = min(cnt[n], (unsigned)MAXDEG);
    if (t < (int)d) nbr[t] = slots[((size_t)n << 7) + t] & 0xFFFu;
    __syncthreads();
    int w = t & 127, h = t >> 7;
    unsigned acc = 0;
    for (unsigned i = (unsigned)h; i < d; i += 2)
        acc |= B[((size_t)nbr[i] << 7) + w];   // 512B coalesced rows, L2-resident
    rowH[h][w] = acc;
    __syncthreads();
    if (t < NWORDS) rowH[0][t] |= rowH[1][t];
    __syncthreads();
    float4* o4 = (float4*)(out_adj + (size_t)p * K_SEL);
    #pragma unroll
    for (int i = 0; i < 2; ++i) {
        int q4 = t + (i << 8);             // 512 float4 per row
        int q = q4 << 2;
        unsigned c0 = permw[q], c1 = permw[q + 1], c2 = permw[q + 2], c3 = permw[q + 3];
        float4 v;
        v.x = (float)((rowH[0][c0 >> 5] >> (c0 & 31)) & 1u);
        v.y = (float)((rowH[0][c1 >> 5] >> (c1 & 31)) & 1u);
        v.z = (float)((rowH[0][c2 >> 5] >> (c2 & 31)) & 1u);
        v.w = (float)((rowH[0][c3 >> 5] >> (c3 & 31)) & 1u);
        o4[q4] = v;
    }
}

extern "C" void kernel_launch(void* const* d_in, const int* in_sizes, int n_in,
                              void* d_out, int out_size, void* d_ws, size_t ws_size,
                              hipStream_t stream) {
    const float* x     = (const float*)d_in[0];
    const int*   eidx  = (const int*)d_in[1];
    const float* att   = (const float*)d_in[2];
    const int*   batch = (const int*)d_in[3];
    const int*   dir_p = (const int*)d_in[4];
    const int* src = eidx;
    const int* dst = eidx + N_EDGES;

    // workspace layout (bytes)
    char* ws = (char*)d_ws;
    unsigned* B      = (unsigned*)(ws + 0);        // 4096*128*4 = 2,097,152
    unsigned* cnt    = (unsigned*)(ws + 2097152);  // 16,384
    float*    scores = (float*)   (ws + 2113536);  // 16,384
    unsigned* permw  = (unsigned*)(ws + 2129920);  // 8,192
    unsigned* slots  = (unsigned*)(ws + 2138112);  // 2,097,152 (end ~4.24 MB)

    // output layout (floats)
    float* out_x     = (float*)d_out;                          // 2048*512
    float* out_adj   = out_x + (size_t)K_SEL * D_FEAT;         // 2048*2048
    float* out_batch = out_adj + (size_t)K_SEL * K_SEL;        // 2048
    float* out_perm  = out_batch + K_SEL;                      // 2048

    zero_cnt<<<N_NODES / 256, 256, 0, stream>>>(cnt);
    build_kernel<<<N_EDGES / 512, 512, 0, stream>>>(src, dst, cnt, slots);
    score_kernel<<<N_NODES / 4, 256, 0, stream>>>(cnt, slots, att, dir_p, scores, B);
    rank_kernel<<<N_NODES / 4, 256, 0, stream>>>(scores, batch, x, permw,
                                                 out_x, out_batch, out_perm);
    adj_kernel<<<K_SEL, 256, 0, stream>>>(permw, cnt, slots, B, out_adj);
}